// Round 4
// baseline (212.811 us; speedup 1.0000x reference)
//
#include <hip/hip_runtime.h>
#include <hip/hip_bf16.h>

#define B_ 2
#define S_ 2048
#define E_ 1024
#define H_ 16
#define D_ 64

typedef __attribute__((ext_vector_type(8))) short short8;    // 8 x bf16 (4 VGPRs)
typedef __attribute__((ext_vector_type(4))) float f32x4;     // 16x16 MFMA C/D
typedef __attribute__((ext_vector_type(16))) float f32x16;   // 32x32 MFMA C/D
typedef __attribute__((ext_vector_type(4))) unsigned short u16x4;

#define AS1 __attribute__((address_space(1)))
#define AS3 __attribute__((address_space(3)))

static __device__ __forceinline__ unsigned short f2bf(float f) {  // RNE
  unsigned int u = __builtin_bit_cast(unsigned int, f);
  return (unsigned short)((u + 0x7fffu + ((u >> 16) & 1u)) >> 16);
}
static __device__ __forceinline__ unsigned short f2bf_f(float f) { // fast round
  unsigned int u = __builtin_bit_cast(unsigned int, f);
  return (unsigned short)((u + 0x8000u) >> 16);
}
static __device__ __forceinline__ void gload_lds16(const void* g, void* l) {
  __builtin_amdgcn_global_load_lds((const AS1 unsigned int*)g, (AS3 unsigned int*)l, 16, 0, 0);
}

// ---------------- fused fp32 -> bf16 convert: 4 weights + x ----------------
// grid (1024, 8): y 0..3 -> weight y into contiguous Wcat; y 4..7 -> quarter of x.
__global__ __launch_bounds__(256) void cvt_all(const float* __restrict__ x,
                                               const float* __restrict__ w0,
                                               const float* __restrict__ w1,
                                               const float* __restrict__ w2,
                                               const float* __restrict__ w3,
                                               unsigned short* __restrict__ xb,
                                               unsigned short* __restrict__ wcat) {
  const int y = blockIdx.y;
  const float* src;
  unsigned short* dst;
  if (y < 4) {
    src = (y == 0) ? w0 : (y == 1) ? w1 : (y == 2) ? w2 : w3;
    dst = wcat + (size_t)y * (E_ * E_);
  } else {
    src = x + (size_t)(y - 4) * (E_ * E_);
    dst = xb + (size_t)(y - 4) * (E_ * E_);
  }
  int i = blockIdx.x * 1024 + threadIdx.x * 4;
  f32x4 v = *(const f32x4*)(src + i);
  u16x4 o;
  o.x = f2bf(v.x); o.y = f2bf(v.y); o.z = f2bf(v.z); o.w = f2bf(v.w);
  *(u16x4*)(dst + i) = o;
}

// ---------------- fused QKV GEMM: C[4096,3072] = x Wcat^T, 128x128 tile ----------------
// n-third 0 -> Q (x0.125, bf16), 1 -> K (bf16), 2 -> V written TRANSPOSED to VT (B,H,D,S).
__global__ __launch_bounds__(256) void gemm_qkv3(const unsigned short* __restrict__ A,
                                                 const unsigned short* __restrict__ W,
                                                 const float* __restrict__ bq,
                                                 const float* __restrict__ bk,
                                                 const float* __restrict__ bv,
                                                 unsigned short* __restrict__ Qo,
                                                 unsigned short* __restrict__ Ko,
                                                 unsigned short* __restrict__ VT) {
  __shared__ unsigned short lA[128 * 32];
  __shared__ unsigned short lB[128 * 32];
  const int K = E_;
  const int tid  = threadIdx.x;
  const int lane = tid & 63;
  const int w    = tid >> 6;
  const int wm   = (w >> 1) * 64, wn = (w & 1) * 64;
  const int li   = lane & 15, quad = lane >> 4;
  const int m0   = blockIdx.x * 128, n0 = blockIdx.y * 128;

  f32x4 acc[4][4];
#pragma unroll
  for (int i = 0; i < 4; ++i)
#pragma unroll
    for (int j = 0; j < 4; ++j) { f32x4 z = {0.f, 0.f, 0.f, 0.f}; acc[i][j] = z; }

  const int r0 = tid >> 2, kc0 = (tid & 3) * 8;
  const unsigned short* a0 = A + (size_t)(m0 + r0) * K + kc0;
  const unsigned short* a1 = A + (size_t)(m0 + r0 + 64) * K + kc0;
  const unsigned short* b0 = W + (size_t)(n0 + r0) * K + kc0;
  const unsigned short* b1 = W + (size_t)(n0 + r0 + 64) * K + kc0;

  for (int k0 = 0; k0 < K; k0 += 32) {
    __syncthreads();
    gload_lds16(a0 + k0, &lA[tid * 8]);
    gload_lds16(a1 + k0, &lA[(tid + 256) * 8]);
    gload_lds16(b0 + k0, &lB[tid * 8]);
    gload_lds16(b1 + k0, &lB[(tid + 256) * 8]);
    __syncthreads();
    short8 af[4], bf[4];
#pragma unroll
    for (int i = 0; i < 4; ++i) af[i] = *(const short8*)&lA[(wm + i * 16 + li) * 32 + quad * 8];
#pragma unroll
    for (int j = 0; j < 4; ++j) bf[j] = *(const short8*)&lB[(wn + j * 16 + li) * 32 + quad * 8];
#pragma unroll
    for (int i = 0; i < 4; ++i)
#pragma unroll
      for (int j = 0; j < 4; ++j)
        acc[i][j] = __builtin_amdgcn_mfma_f32_16x16x32_bf16(af[i], bf[j], acc[i][j], 0, 0, 0);
  }

  const int third = blockIdx.y >> 3;   // 0:Q 1:K 2:V (uniform per block)
  if (third < 2) {
    unsigned short* C = (third == 0) ? Qo : Ko;
    const float* bias = (third == 0) ? bq : bk;
    const float sc = (third == 0) ? 0.125f : 1.0f;
#pragma unroll
    for (int j = 0; j < 4; ++j) {
      int colf = (n0 & 1023) + wn + j * 16 + li;
      float bvv = bias[colf];
#pragma unroll
      for (int i = 0; i < 4; ++i)
#pragma unroll
        for (int r = 0; r < 4; ++r) {
          int row = m0 + wm + i * 16 + quad * 4 + r;
          C[(size_t)row * E_ + colf] = f2bf_f((acc[i][j][r] + bvv) * sc);
        }
    }
  } else {
    // V third: write transposed, VT[((b*16+h)*64+d)*2048 + s], 4 consecutive s packed
#pragma unroll
    for (int j = 0; j < 4; ++j) {
      int colf = (n0 & 1023) + wn + j * 16 + li;
      int h2 = colf >> 6, d2 = colf & 63;
      float bvv = bv[colf];
#pragma unroll
      for (int i = 0; i < 4; ++i) {
        int srow = m0 + wm + i * 16 + quad * 4;       // global b*S+s, 4 consecutive
        int bb = srow >> 11, s2 = srow & 2047;
        u16x4 o;
        o.x = f2bf_f(acc[i][j][0] + bvv);
        o.y = f2bf_f(acc[i][j][1] + bvv);
        o.z = f2bf_f(acc[i][j][2] + bvv);
        o.w = f2bf_f(acc[i][j][3] + bvv);
        *(u16x4*)&VT[(((size_t)bb * 16 + h2) * 64 + d2) * 2048 + s2] = o;
      }
    }
  }
}

// ---------------- output GEMM: 64x128 tile (grid 512 = 2 blocks/CU), fp32 out ----------------
__global__ __launch_bounds__(256) void gemm_out64(const unsigned short* __restrict__ A,
                                                  const unsigned short* __restrict__ W,
                                                  const float* __restrict__ bias,
                                                  float* __restrict__ C) {
  __shared__ unsigned short lA[64 * 32];
  __shared__ unsigned short lB[128 * 32];
  const int N = E_, K = E_;
  const int tid  = threadIdx.x;
  const int lane = tid & 63;
  const int w    = tid >> 6;
  const int m0   = blockIdx.x * 64, n0 = blockIdx.y * 128;
  const int mi   = (w >> 1) * 32, ni = (w & 1) * 64;
  const int li   = lane & 15, quad = lane >> 4, koff = quad * 8;

  f32x4 acc[2][4];
#pragma unroll
  for (int i = 0; i < 2; ++i)
#pragma unroll
    for (int j = 0; j < 4; ++j) { f32x4 z = {0.f, 0.f, 0.f, 0.f}; acc[i][j] = z; }

  const int arow = tid >> 2, ak = (tid & 3) * 8;
  const int b2 = tid + 256;

  for (int k0 = 0; k0 < K; k0 += 32) {
    __syncthreads();
    gload_lds16(A + (size_t)(m0 + arow) * K + k0 + ak, &lA[tid * 8]);
    gload_lds16(W + (size_t)(n0 + arow) * K + k0 + ak, &lB[tid * 8]);
    gload_lds16(W + (size_t)(n0 + (b2 >> 2)) * K + k0 + (b2 & 3) * 8, &lB[b2 * 8]);
    __syncthreads();
    short8 a0 = *(const short8*)&lA[(mi      + li) * 32 + koff];
    short8 a1 = *(const short8*)&lA[(mi + 16 + li) * 32 + koff];
#pragma unroll
    for (int nt = 0; nt < 4; ++nt) {
      short8 bb = *(const short8*)&lB[(ni + nt * 16 + li) * 32 + koff];
      acc[0][nt] = __builtin_amdgcn_mfma_f32_16x16x32_bf16(a0, bb, acc[0][nt], 0, 0, 0);
      acc[1][nt] = __builtin_amdgcn_mfma_f32_16x16x32_bf16(a1, bb, acc[1][nt], 0, 0, 0);
    }
  }

#pragma unroll
  for (int mt = 0; mt < 2; ++mt)
#pragma unroll
    for (int nt = 0; nt < 4; ++nt) {
      int col = n0 + ni + nt * 16 + li;
      float bvv = bias[col];
#pragma unroll
      for (int r = 0; r < 4; ++r) {
        int row = m0 + mi + mt * 16 + quad * 4 + r;
        C[(size_t)row * N + col] = acc[mt][nt][r] + bvv;
      }
    }
}

// ---------------- flash attention, 32x32x16 MFMA, S^T orientation ----------------
// grid (S/128, H, B), 512 thr = 8 waves: (wq 0..3) x (wt 0..1).
// Wave (wq,wt): q-cols 32*wq..+31, t-half 64*wt..+63 of each 128-t tile.
// S^T = K.Q^T  -> C layout puts q in lanes (col=lane&31), t in regs: softmax
// row-sums are IN-LANE; P^T stays in registers (lane-pair exchange feeds it as
// the B operand of O^T = V^T.P^T). Zero P LDS traffic. Q frags hoisted.
// LDS: XOR-swizzled 16B chunks (chunk ^ (row&7)), staged via global_load_lds.
__global__ __launch_bounds__(512, 4) void attn_kernel(const unsigned short* __restrict__ Q,
                                                      const unsigned short* __restrict__ Kp,
                                                      const unsigned short* __restrict__ VT,
                                                      const float* __restrict__ qw,
                                                      const float* __restrict__ qb,
                                                      unsigned short* __restrict__ O) {
  __shared__ __align__(16) char smem[49152];
  unsigned short* Qs = (unsigned short*)smem;            // [128 q][64 d]   16 KB
  unsigned short* Ks = (unsigned short*)(smem + 16384);  // [128 t][64 d]   16 KB
  unsigned short* Vs = (unsigned short*)(smem + 32768);  // [64 d][128 t]   16 KB
  float* Rbuf = (float*)(smem + 16384);                  // final reduce: 4x64x32 f32 = 32 KB
  float* Lbuf = (float*)smem;                            // final reduce: 4x64 f32

  const int tid  = threadIdx.x;
  const int lane = tid & 63;
  const int c    = lane & 31, hi = lane >> 5;
  const int wv   = tid >> 6, wq = wv & 3, wt = wv >> 2;
  const int s0 = blockIdx.x * 128, h = blockIdx.y, b = blockIdx.z;
  const int cm7 = c & 7;

  { // Q staging: 1024 swizzled chunks
    int p = tid, row = p >> 3, kc = (p & 7) ^ (row & 7);
    gload_lds16(Q + (size_t)(b * S_ + s0 + row) * E_ + h * 64 + kc * 8, &Qs[p * 8]);
    p = tid + 512; row = p >> 3; kc = (p & 7) ^ (row & 7);
    gload_lds16(Q + (size_t)(b * S_ + s0 + row) * E_ + h * 64 + kc * 8, &Qs[p * 8]);
  }
  // K/V staging source pointers (advance by 128 t per iter)
  const int kr1 = tid >> 3, kr2 = (tid + 512) >> 3;
  const unsigned short* kg1 = Kp + (size_t)(b * S_ + kr1) * E_ + h * 64 + (((tid & 7) ^ (kr1 & 7)) * 8);
  const unsigned short* kg2 = Kp + (size_t)(b * S_ + kr2) * E_ + h * 64 + ((((tid + 512) & 7) ^ (kr2 & 7)) * 8);
  const int vr1 = tid >> 4, vr2 = (tid + 512) >> 4;
  const unsigned short* vg1 = VT + ((size_t)((b * H_ + h) * 64 + vr1)) * S_ + (((tid & 15) ^ (vr1 & 7)) * 8);
  const unsigned short* vg2 = VT + ((size_t)((b * H_ + h) * 64 + vr2)) * S_ + ((((tid + 512) & 15) ^ (vr2 & 7)) * 8);

  __syncthreads();  // Q staged

  // hoisted Q^T B-frags: B[k=d][n=q], lane n=c -> row wq*32+c, d-chunk 2k+hi
  short8 qf[4];
#pragma unroll
  for (int kk = 0; kk < 4; ++kk)
    qf[kk] = *(const short8*)&Qs[(wq * 32 + c) * 64 + (((2 * kk + hi) ^ cm7) << 3)];

  f32x16 ot[2];
#pragma unroll
  for (int d = 0; d < 2; ++d)
#pragma unroll
    for (int i = 0; i < 16; ++i) ot[d][i] = 0.f;
  float lacc = 0.f;

  for (int tt = 0; tt < S_ / 128; ++tt) {
    if (tt) __syncthreads();
    gload_lds16(kg1, &Ks[tid * 8]);
    gload_lds16(kg2, &Ks[(tid + 512) * 8]);
    gload_lds16(vg1, &Vs[tid * 8]);
    gload_lds16(vg2, &Vs[(tid + 512) * 8]);
    kg1 += (size_t)128 * E_; kg2 += (size_t)128 * E_;
    vg1 += 128; vg2 += 128;
    __syncthreads();

    // S^T = K . Q^T : tiles tau over this wave's 64-t half
    f32x16 st[2];
#pragma unroll
    for (int d = 0; d < 2; ++d)
#pragma unroll
      for (int i = 0; i < 16; ++i) st[d][i] = 0.f;
#pragma unroll
    for (int tau = 0; tau < 2; ++tau) {
      const int trow = 64 * wt + 32 * tau + c;
#pragma unroll
      for (int kk = 0; kk < 4; ++kk) {
        short8 kf = *(const short8*)&Ks[trow * 64 + (((2 * kk + hi) ^ cm7) << 3)];
        st[tau] = __builtin_amdgcn_mfma_f32_32x32x16_bf16(kf, qf[kk], st[tau], 0, 0, 0);
      }
    }

    // p = exp(s): all values for q-col = wq*32+c live in-lane. Pack to bf16 pairs.
    unsigned int pk[2][8];
#pragma unroll
    for (int tau = 0; tau < 2; ++tau)
#pragma unroll
      for (int m = 0; m < 4; ++m)
#pragma unroll
        for (int u = 0; u < 2; ++u) {
          float p0 = __expf(st[tau][4 * m + 2 * u]);
          float p1 = __expf(st[tau][4 * m + 2 * u + 1]);
          lacc += p0 + p1;
          pk[tau][2 * m + u] = (unsigned int)f2bf_f(p0) | ((unsigned int)f2bf_f(p1) << 16);
        }

    // O^T += V^T . P^T : P^T frag j from regs via lane-pair (xor 32) exchange.
    // Frag j (t = 16j+8hi+e): tau=j>>1, quads m=2(j&1)+hi; low e-half from lane(c,0),
    // high from lane(c,1) -> exchange the quad the partner needs, then assemble.
#pragma unroll
    for (int pp = 0; pp < 2; ++pp)
#pragma unroll
      for (int tau = 0; tau < 2; ++tau) {
        unsigned int q0a = pk[tau][4 * pp + 0], q0b = pk[tau][4 * pp + 1];  // quad m=2pp
        unsigned int q1a = pk[tau][4 * pp + 2], q1b = pk[tau][4 * pp + 3];  // quad m=2pp+1
        unsigned int sa = hi ? q0a : q1a, sb = hi ? q0b : q1b;   // partner's need
        unsigned int ra = (unsigned int)__shfl_xor((int)sa, 32, 64);
        unsigned int rb = (unsigned int)__shfl_xor((int)sb, 32, 64);
        unsigned int oa = hi ? q1a : q0a, ob = hi ? q1b : q0b;   // own quad
        unsigned int l0 = hi ? ra : oa, l1 = hi ? rb : ob;       // e=0..3
        unsigned int h0 = hi ? oa : ra, h1 = hi ? ob : rb;       // e=4..7
        union { unsigned int u[4]; short8 s; } bf;
        bf.u[0] = l0; bf.u[1] = l1; bf.u[2] = h0; bf.u[3] = h1;
        const int j = 2 * tau + pp;
#pragma unroll
        for (int dd = 0; dd < 2; ++dd) {
          short8 vf = *(const short8*)&Vs[(32 * dd + c) * 128 + (((8 * wt + 2 * j + hi) ^ cm7) << 3)];
          ot[dd] = __builtin_amdgcn_mfma_f32_32x32x16_bf16(vf, bf.s, ot[dd], 0, 0, 0);
        }
      }
  }

  // combine the two t-interleavings held by lane pair (c,0)/(c,1)
  float l2 = lacc + __shfl_xor(lacc, 32, 64);

  __syncthreads();  // done with Ks/Vs; reuse as Rbuf
  if (wt == 1) {
#pragma unroll
    for (int dd = 0; dd < 2; ++dd)
#pragma unroll
      for (int i = 0; i < 16; ++i) Rbuf[(wq * 64 + lane) * 32 + dd * 16 + i] = ot[dd][i];
    Lbuf[wq * 64 + lane] = l2;
  }
  __syncthreads();
  if (wt == 0) {
    float lt = l2 + Lbuf[wq * 64 + lane];
    float scale = 1.0f;
    if (h < 2) scale = cosf(qw[h] * (1.0f / (float)S_) + qb[h]);
    float inv = scale / lt;
    const int q = s0 + wq * 32 + c;
    unsigned short* obase = O + (size_t)(b * S_ + q) * E_ + h * 64;
#pragma unroll
    for (int dd = 0; dd < 2; ++dd)
#pragma unroll
      for (int m = 0; m < 4; ++m) {
        u16x4 o;
#pragma unroll
        for (int r = 0; r < 4; ++r) {
          float v = (ot[dd][4 * m + r] + Rbuf[(wq * 64 + lane) * 32 + dd * 16 + 4 * m + r]) * inv;
          ((unsigned short*)&o)[r] = f2bf_f(v);
        }
        *(u16x4*)(obase + 32 * dd + 8 * m + 4 * hi) = o;
      }
  }
}

extern "C" void kernel_launch(void* const* d_in, const int* in_sizes, int n_in,
                              void* d_out, int out_size, void* d_ws, size_t ws_size,
                              hipStream_t stream) {
  const float* x  = (const float*)d_in[0];
  const float* Wq = (const float*)d_in[1];
  const float* bq = (const float*)d_in[2];
  const float* Wk = (const float*)d_in[3];
  const float* bk = (const float*)d_in[4];
  const float* Wv = (const float*)d_in[5];
  const float* bv = (const float*)d_in[6];
  const float* Wo = (const float*)d_in[7];
  const float* bo = (const float*)d_in[8];
  const float* qw = (const float*)d_in[9];
  const float* qb = (const float*)d_in[10];
  float* out = (float*)d_out;

  char* ws = (char*)d_ws;
  const size_t MB = 1u << 20;
  unsigned short* xb   = (unsigned short*)(ws + 0 * MB);   // 8 MB
  unsigned short* Wcat = (unsigned short*)(ws + 8 * MB);   // 4 x 2 MB: Wq,Wk,Wv,Wo
  unsigned short* Qb   = (unsigned short*)(ws + 16 * MB);  // 8 MB
  unsigned short* Kb   = (unsigned short*)(ws + 24 * MB);  // 8 MB
  unsigned short* VTb  = (unsigned short*)(ws + 32 * MB);  // 8 MB
  unsigned short* Ob   = (unsigned short*)(ws + 40 * MB);  // 8 MB
  unsigned short* Wob  = Wcat + (size_t)3 * E_ * E_;

  cvt_all<<<dim3(1024, 8), 256, 0, stream>>>(x, Wq, Wk, Wv, Wo, xb, Wcat);

  gemm_qkv3<<<dim3(32, 24), 256, 0, stream>>>(xb, Wcat, bq, bk, bv, Qb, Kb, VTb);

  attn_kernel<<<dim3(S_ / 128, H_, B_), 512, 0, stream>>>(Qb, Kb, VTb, qw, qb, Ob);

  gemm_out64<<<dim3(64, 8), 256, 0, stream>>>(Ob, Wob, bo, out);
}

// Round 5
// 201.614 us; speedup vs baseline: 1.0555x; 1.0555x over previous
//
#include <hip/hip_runtime.h>
#include <hip/hip_bf16.h>

#define B_ 2
#define S_ 2048
#define E_ 1024
#define H_ 16
#define D_ 64

typedef __attribute__((ext_vector_type(8))) short short8;    // 8 x bf16 (4 VGPRs)
typedef __attribute__((ext_vector_type(4))) float f32x4;     // 16x16 MFMA C/D
typedef __attribute__((ext_vector_type(16))) float f32x16;   // 32x32 MFMA C/D
typedef __attribute__((ext_vector_type(4))) unsigned short u16x4;

#define AS1 __attribute__((address_space(1)))
#define AS3 __attribute__((address_space(3)))

static __device__ __forceinline__ unsigned short f2bf(float f) {  // RNE
  unsigned int u = __builtin_bit_cast(unsigned int, f);
  return (unsigned short)((u + 0x7fffu + ((u >> 16) & 1u)) >> 16);
}
static __device__ __forceinline__ unsigned short f2bf_f(float f) { // fast round
  unsigned int u = __builtin_bit_cast(unsigned int, f);
  return (unsigned short)((u + 0x8000u) >> 16);
}
static __device__ __forceinline__ void gload_lds16(const void* g, void* l) {
  __builtin_amdgcn_global_load_lds((const AS1 unsigned int*)g, (AS3 unsigned int*)l, 16, 0, 0);
}

// ---------------- fused fp32 -> bf16 convert: 4 weights + x ----------------
__global__ __launch_bounds__(256) void cvt_all(const float* __restrict__ x,
                                               const float* __restrict__ w0,
                                               const float* __restrict__ w1,
                                               const float* __restrict__ w2,
                                               const float* __restrict__ w3,
                                               unsigned short* __restrict__ xb,
                                               unsigned short* __restrict__ wcat) {
  const int y = blockIdx.y;
  const float* src;
  unsigned short* dst;
  if (y < 4) {
    src = (y == 0) ? w0 : (y == 1) ? w1 : (y == 2) ? w2 : w3;
    dst = wcat + (size_t)y * (E_ * E_);
  } else {
    src = x + (size_t)(y - 4) * (E_ * E_);
    dst = xb + (size_t)(y - 4) * (E_ * E_);
  }
  int i = blockIdx.x * 1024 + threadIdx.x * 4;
  f32x4 v = *(const f32x4*)(src + i);
  u16x4 o;
  o.x = f2bf(v.x); o.y = f2bf(v.y); o.z = f2bf(v.z); o.w = f2bf(v.w);
  *(u16x4*)(dst + i) = o;
}

// ---------------- fused QKV GEMM: 128x128 tile, BK=64, swizzled LDS ----------------
// n-third 0 -> Q (x0.125), 1 -> K, 2 -> V written transposed to VT via LDS transpose.
__global__ __launch_bounds__(256) void gemm_qkv3(const unsigned short* __restrict__ A,
                                                 const unsigned short* __restrict__ W,
                                                 const float* __restrict__ bq,
                                                 const float* __restrict__ bk,
                                                 const float* __restrict__ bv,
                                                 unsigned short* __restrict__ Qo,
                                                 unsigned short* __restrict__ Ko,
                                                 unsigned short* __restrict__ VT) {
  __shared__ __align__(16) unsigned short sm[128 * 64 * 2];   // lA | lB, 32 KB
  unsigned short* lA = sm;
  unsigned short* lB = sm + 128 * 64;
  const int K = E_;
  const int tid  = threadIdx.x;
  const int lane = tid & 63;
  const int w    = tid >> 6;
  const int wm   = (w >> 1) * 64, wn = (w & 1) * 64;
  const int li   = lane & 15, quad = lane >> 4;
  const int e7   = li & 7;
  const int m0   = blockIdx.x * 128, n0 = blockIdx.y * 128;

  f32x4 acc[4][4];
#pragma unroll
  for (int i = 0; i < 4; ++i)
#pragma unroll
    for (int j = 0; j < 4; ++j) { f32x4 z = {0.f, 0.f, 0.f, 0.f}; acc[i][j] = z; }

  // staging: 1024 16B chunks per matrix; chunk p -> row p>>3, swizzled k-chunk (p&7)^(row&7)
  const unsigned short* pA[4];
  const unsigned short* pB[4];
#pragma unroll
  for (int q = 0; q < 4; ++q) {
    int p = tid + 256 * q, row = p >> 3, kc = (p & 7) ^ (row & 7);
    pA[q] = A + (size_t)(m0 + row) * K + kc * 8;
    pB[q] = W + (size_t)(n0 + row) * K + kc * 8;
  }

  for (int k0 = 0; k0 < K; k0 += 64) {
    __syncthreads();
#pragma unroll
    for (int q = 0; q < 4; ++q) gload_lds16(pA[q] + k0, &lA[(tid + 256 * q) * 8]);
#pragma unroll
    for (int q = 0; q < 4; ++q) gload_lds16(pB[q] + k0, &lB[(tid + 256 * q) * 8]);
    __syncthreads();
#pragma unroll
    for (int ks = 0; ks < 2; ++ks) {
      short8 af[4], bf[4];
#pragma unroll
      for (int i = 0; i < 4; ++i)
        af[i] = *(const short8*)&lA[(wm + i * 16 + li) * 64 + (((ks * 4 + quad) ^ e7) << 3)];
#pragma unroll
      for (int j = 0; j < 4; ++j)
        bf[j] = *(const short8*)&lB[(wn + j * 16 + li) * 64 + (((ks * 4 + quad) ^ e7) << 3)];
#pragma unroll
      for (int i = 0; i < 4; ++i)
#pragma unroll
        for (int j = 0; j < 4; ++j)
          acc[i][j] = __builtin_amdgcn_mfma_f32_16x16x32_bf16(af[i], bf[j], acc[i][j], 0, 0, 0);
    }
  }

  const int third = blockIdx.y >> 3;   // 0:Q 1:K 2:V (uniform per block)
  if (third < 2) {
    unsigned short* C = (third == 0) ? Qo : Ko;
    const float* bias = (third == 0) ? bq : bk;
    const float sc = (third == 0) ? 0.125f : 1.0f;
#pragma unroll
    for (int j = 0; j < 4; ++j) {
      int colf = (n0 & 1023) + wn + j * 16 + li;
      float bvv = bias[colf];
#pragma unroll
      for (int i = 0; i < 4; ++i)
#pragma unroll
        for (int r = 0; r < 4; ++r) {
          int row = m0 + wm + i * 16 + quad * 4 + r;
          C[(size_t)row * E_ + colf] = f2bf_f((acc[i][j][r] + bvv) * sc);
        }
    }
  } else {
    // V third: transpose in LDS (reuse sm: 128 cols x 128 s, 16-chunk swizzle per col-row)
    const int base = (blockIdx.y & 7) * 128;
    __syncthreads();   // all waves done with lA/lB frag reads
#pragma unroll
    for (int j = 0; j < 4; ++j) {
      int col = wn + j * 16 + li;
      float bvv = bv[base + col];
      int cm15 = col & 15;
#pragma unroll
      for (int i = 0; i < 4; ++i) {
        int s = wm + i * 16 + quad * 4;
        int off = col * 128 + (((s >> 3) ^ cm15) << 3) + (s & 7);
        u16x4 o;
        o.x = f2bf_f(acc[i][j][0] + bvv);
        o.y = f2bf_f(acc[i][j][1] + bvv);
        o.z = f2bf_f(acc[i][j][2] + bvv);
        o.w = f2bf_f(acc[i][j][3] + bvv);
        *(u16x4*)&sm[off] = o;
      }
    }
    __syncthreads();
    // coalesced store: 2 threads per col, 64 s each (8 x 16B contiguous)
    int col = tid >> 1, half = tid & 1;
    int colf = base + col;
    int h2 = colf >> 6, d2 = colf & 63;
    int bb = m0 >> 11, s2 = m0 & 2047;
    unsigned short* dst = VT + (((size_t)bb * 16 + h2) * 64 + d2) * 2048 + s2 + half * 64;
    int cm15 = col & 15;
#pragma unroll
    for (int u = 0; u < 8; ++u) {
      int sc2 = half * 8 + u;
      *(short8*)(dst + u * 8) = *(const short8*)&sm[col * 128 + ((sc2 ^ cm15) << 3)];
    }
  }
}

// ---------------- output GEMM: 64x128 tile, BK=64, swizzled, fp32 out ----------------
__global__ __launch_bounds__(256) void gemm_out64(const unsigned short* __restrict__ A,
                                                  const unsigned short* __restrict__ W,
                                                  const float* __restrict__ bias,
                                                  float* __restrict__ C) {
  __shared__ __align__(16) unsigned short lA[64 * 64];    // 8 KB
  __shared__ __align__(16) unsigned short lB[128 * 64];   // 16 KB
  const int N = E_, K = E_;
  const int tid  = threadIdx.x;
  const int lane = tid & 63;
  const int w    = tid >> 6;
  const int m0   = blockIdx.x * 64, n0 = blockIdx.y * 128;
  const int mi   = (w >> 1) * 32, ni = (w & 1) * 64;
  const int li   = lane & 15, quad = lane >> 4;
  const int e7   = li & 7;

  f32x4 acc[2][4];
#pragma unroll
  for (int i = 0; i < 2; ++i)
#pragma unroll
    for (int j = 0; j < 4; ++j) { f32x4 z = {0.f, 0.f, 0.f, 0.f}; acc[i][j] = z; }

  const unsigned short* pA[2];
  const unsigned short* pB[4];
#pragma unroll
  for (int q = 0; q < 2; ++q) {
    int p = tid + 256 * q, row = p >> 3, kc = (p & 7) ^ (row & 7);
    pA[q] = A + (size_t)(m0 + row) * K + kc * 8;
  }
#pragma unroll
  for (int q = 0; q < 4; ++q) {
    int p = tid + 256 * q, row = p >> 3, kc = (p & 7) ^ (row & 7);
    pB[q] = W + (size_t)(n0 + row) * K + kc * 8;
  }

  for (int k0 = 0; k0 < K; k0 += 64) {
    __syncthreads();
#pragma unroll
    for (int q = 0; q < 2; ++q) gload_lds16(pA[q] + k0, &lA[(tid + 256 * q) * 8]);
#pragma unroll
    for (int q = 0; q < 4; ++q) gload_lds16(pB[q] + k0, &lB[(tid + 256 * q) * 8]);
    __syncthreads();
#pragma unroll
    for (int ks = 0; ks < 2; ++ks) {
      short8 a0 = *(const short8*)&lA[(mi      + li) * 64 + (((ks * 4 + quad) ^ e7) << 3)];
      short8 a1 = *(const short8*)&lA[(mi + 16 + li) * 64 + (((ks * 4 + quad) ^ e7) << 3)];
#pragma unroll
      for (int nt = 0; nt < 4; ++nt) {
        short8 bb = *(const short8*)&lB[(ni + nt * 16 + li) * 64 + (((ks * 4 + quad) ^ e7) << 3)];
        acc[0][nt] = __builtin_amdgcn_mfma_f32_16x16x32_bf16(a0, bb, acc[0][nt], 0, 0, 0);
        acc[1][nt] = __builtin_amdgcn_mfma_f32_16x16x32_bf16(a1, bb, acc[1][nt], 0, 0, 0);
      }
    }
  }

#pragma unroll
  for (int mt = 0; mt < 2; ++mt)
#pragma unroll
    for (int nt = 0; nt < 4; ++nt) {
      int col = n0 + ni + nt * 16 + li;
      float bvv = bias[col];
#pragma unroll
      for (int r = 0; r < 4; ++r) {
        int row = m0 + mi + mt * 16 + quad * 4 + r;
        C[(size_t)row * N + col] = acc[mt][nt][r] + bvv;
      }
    }
}

// ---------------- flash attention, 32x32x16 MFMA, S^T orientation, K/V dbuf ----------------
// grid (S/128, H, B), 512 thr = 8 waves (wq 0..3) x (wt 0..1).
// Double-buffered K/V: prefetch for tile tt+1 is issued right after the barrier,
// so the global_load_lds DMA overlaps the whole compute of tile tt; ONE barrier/iter.
// LDS 80 KB -> exactly 2 blocks/CU (grid 512 = 2/CU anyway, so the extra LDS is free).
__global__ __launch_bounds__(512, 4) void attn_kernel(const unsigned short* __restrict__ Q,
                                                      const unsigned short* __restrict__ Kp,
                                                      const unsigned short* __restrict__ VT,
                                                      const float* __restrict__ qw,
                                                      const float* __restrict__ qb,
                                                      unsigned short* __restrict__ O) {
  __shared__ __align__(16) char smem[81920];
  unsigned short* Qs = (unsigned short*)smem;                    // [128 q][64 d] 16 KB
  unsigned short* KsB0 = (unsigned short*)(smem + 16384);        // buf0 K 16 KB
  unsigned short* VsB0 = (unsigned short*)(smem + 32768);        // buf0 V 16 KB
  unsigned short* KsB1 = (unsigned short*)(smem + 49152);        // buf1 K 16 KB
  unsigned short* VsB1 = (unsigned short*)(smem + 65536);        // buf1 V 16 KB
  float* Rbuf = (float*)(smem + 16384);   // epilogue: 4 x 64 x 33 f32 (padded, conflict-free)
  float* Lbuf = (float*)smem;             // epilogue: 4 x 64 f32

  const int tid  = threadIdx.x;
  const int lane = tid & 63;
  const int c    = lane & 31, hi = lane >> 5;
  const int wv   = tid >> 6, wq = wv & 3, wt = wv >> 2;
  const int s0 = blockIdx.x * 128, h = blockIdx.y, b = blockIdx.z;
  const int cm7 = c & 7;

  { // Q staging: 1024 swizzled chunks
    int p = tid, row = p >> 3, kc = (p & 7) ^ (row & 7);
    gload_lds16(Q + (size_t)(b * S_ + s0 + row) * E_ + h * 64 + kc * 8, &Qs[p * 8]);
    p = tid + 512; row = p >> 3; kc = (p & 7) ^ (row & 7);
    gload_lds16(Q + (size_t)(b * S_ + s0 + row) * E_ + h * 64 + kc * 8, &Qs[p * 8]);
  }
  // K/V staging source pointers (advance 128 t per tile)
  const int kr1 = tid >> 3, kr2 = (tid + 512) >> 3;
  const unsigned short* kg1 = Kp + (size_t)(b * S_ + kr1) * E_ + h * 64 + (((tid & 7) ^ (kr1 & 7)) * 8);
  const unsigned short* kg2 = Kp + (size_t)(b * S_ + kr2) * E_ + h * 64 + ((((tid + 512) & 7) ^ (kr2 & 7)) * 8);
  const int vr1 = tid >> 4, vr2 = (tid + 512) >> 4;
  const unsigned short* vg1 = VT + ((size_t)((b * H_ + h) * 64 + vr1)) * S_ + (((tid & 15) ^ (vr1 & 7)) * 8);
  const unsigned short* vg2 = VT + ((size_t)((b * H_ + h) * 64 + vr2)) * S_ + ((((tid + 512) & 15) ^ (vr2 & 7)) * 8);

  // prologue: stage tile 0 into buf0
  gload_lds16(kg1, &KsB0[tid * 8]);
  gload_lds16(kg2, &KsB0[(tid + 512) * 8]);
  gload_lds16(vg1, &VsB0[tid * 8]);
  gload_lds16(vg2, &VsB0[(tid + 512) * 8]);
  kg1 += (size_t)128 * E_; kg2 += (size_t)128 * E_;
  vg1 += 128; vg2 += 128;
  __syncthreads();

  // hoisted Q^T B-frags
  short8 qf[4];
#pragma unroll
  for (int kk = 0; kk < 4; ++kk)
    qf[kk] = *(const short8*)&Qs[(wq * 32 + c) * 64 + (((2 * kk + hi) ^ cm7) << 3)];

  f32x16 ot[2];
#pragma unroll
  for (int d = 0; d < 2; ++d)
#pragma unroll
    for (int i = 0; i < 16; ++i) ot[d][i] = 0.f;
  float lacc = 0.f;

#pragma unroll 2
  for (int tt = 0; tt < S_ / 128; ++tt) {
    // prefetch next tile into the other buffer (overlaps compute below)
    if (tt < S_ / 128 - 1) {
      unsigned short* Kn = ((tt + 1) & 1) ? KsB1 : KsB0;
      unsigned short* Vn = ((tt + 1) & 1) ? VsB1 : VsB0;
      gload_lds16(kg1, &Kn[tid * 8]);
      gload_lds16(kg2, &Kn[(tid + 512) * 8]);
      gload_lds16(vg1, &Vn[tid * 8]);
      gload_lds16(vg2, &Vn[(tid + 512) * 8]);
      kg1 += (size_t)128 * E_; kg2 += (size_t)128 * E_;
      vg1 += 128; vg2 += 128;
    }
    const unsigned short* Ks = (tt & 1) ? KsB1 : KsB0;
    const unsigned short* Vs = (tt & 1) ? VsB1 : VsB0;

    // S^T = K . Q^T
    f32x16 st[2];
#pragma unroll
    for (int d = 0; d < 2; ++d)
#pragma unroll
      for (int i = 0; i < 16; ++i) st[d][i] = 0.f;
#pragma unroll
    for (int tau = 0; tau < 2; ++tau) {
      const int trow = 64 * wt + 32 * tau + c;
#pragma unroll
      for (int kk = 0; kk < 4; ++kk) {
        short8 kf = *(const short8*)&Ks[trow * 64 + (((2 * kk + hi) ^ cm7) << 3)];
        st[tau] = __builtin_amdgcn_mfma_f32_32x32x16_bf16(kf, qf[kk], st[tau], 0, 0, 0);
      }
    }

    // p = exp(s): in-lane for q-col = wq*32+c; pack bf16 pairs
    unsigned int pk[2][8];
#pragma unroll
    for (int tau = 0; tau < 2; ++tau)
#pragma unroll
      for (int m = 0; m < 4; ++m)
#pragma unroll
        for (int u = 0; u < 2; ++u) {
          float p0 = __expf(st[tau][4 * m + 2 * u]);
          float p1 = __expf(st[tau][4 * m + 2 * u + 1]);
          lacc += p0 + p1;
          pk[tau][2 * m + u] = (unsigned int)f2bf_f(p0) | ((unsigned int)f2bf_f(p1) << 16);
        }

    // O^T += V^T . P^T (P^T assembled in-regs via lane-pair exchange)
#pragma unroll
    for (int pp = 0; pp < 2; ++pp)
#pragma unroll
      for (int tau = 0; tau < 2; ++tau) {
        unsigned int q0a = pk[tau][4 * pp + 0], q0b = pk[tau][4 * pp + 1];
        unsigned int q1a = pk[tau][4 * pp + 2], q1b = pk[tau][4 * pp + 3];
        unsigned int sa = hi ? q0a : q1a, sb = hi ? q0b : q1b;
        unsigned int ra = (unsigned int)__shfl_xor((int)sa, 32, 64);
        unsigned int rb = (unsigned int)__shfl_xor((int)sb, 32, 64);
        unsigned int oa = hi ? q1a : q0a, ob = hi ? q1b : q0b;
        unsigned int l0 = hi ? ra : oa, l1 = hi ? rb : ob;
        unsigned int h0 = hi ? oa : ra, h1 = hi ? ob : rb;
        union { unsigned int u[4]; short8 s; } bf;
        bf.u[0] = l0; bf.u[1] = l1; bf.u[2] = h0; bf.u[3] = h1;
        const int j = 2 * tau + pp;
#pragma unroll
        for (int dd = 0; dd < 2; ++dd) {
          short8 vf = *(const short8*)&Vs[(32 * dd + c) * 128 + (((8 * wt + 2 * j + hi) ^ cm7) << 3)];
          ot[dd] = __builtin_amdgcn_mfma_f32_32x32x16_bf16(vf, bf.s, ot[dd], 0, 0, 0);
        }
      }
    __syncthreads();   // prefetch drained; all waves done with this tile's buffers
  }

  // combine lane pair (c,0)/(c,1)
  float l2 = lacc + __shfl_xor(lacc, 32, 64);

  if (wt == 1) {   // padded stride 33: bank = (lane + idx) % 32 -> 2-way max
#pragma unroll
    for (int dd = 0; dd < 2; ++dd)
#pragma unroll
      for (int i = 0; i < 16; ++i) Rbuf[(wq * 64 + lane) * 33 + dd * 16 + i] = ot[dd][i];
    Lbuf[wq * 64 + lane] = l2;
  }
  __syncthreads();
  if (wt == 0) {
    float lt = l2 + Lbuf[wq * 64 + lane];
    float scale = 1.0f;
    if (h < 2) scale = cosf(qw[h] * (1.0f / (float)S_) + qb[h]);
    float inv = scale / lt;
    const int q = s0 + wq * 32 + c;
    unsigned short* obase = O + (size_t)(b * S_ + q) * E_ + h * 64;
#pragma unroll
    for (int dd = 0; dd < 2; ++dd)
#pragma unroll
      for (int m = 0; m < 4; ++m) {
        u16x4 o;
#pragma unroll
        for (int r = 0; r < 4; ++r) {
          float v = (ot[dd][4 * m + r] + Rbuf[(wq * 64 + lane) * 33 + dd * 16 + 4 * m + r]) * inv;
          ((unsigned short*)&o)[r] = f2bf_f(v);
        }
        *(u16x4*)(obase + 32 * dd + 8 * m + 4 * hi) = o;
      }
  }
}

extern "C" void kernel_launch(void* const* d_in, const int* in_sizes, int n_in,
                              void* d_out, int out_size, void* d_ws, size_t ws_size,
                              hipStream_t stream) {
  const float* x  = (const float*)d_in[0];
  const float* Wq = (const float*)d_in[1];
  const float* bq = (const float*)d_in[2];
  const float* Wk = (const float*)d_in[3];
  const float* bk = (const float*)d_in[4];
  const float* Wv = (const float*)d_in[5];
  const float* bv = (const float*)d_in[6];
  const float* Wo = (const float*)d_in[7];
  const float* bo = (const float*)d_in[8];
  const float* qw = (const float*)d_in[9];
  const float* qb = (const float*)d_in[10];
  float* out = (float*)d_out;

  char* ws = (char*)d_ws;
  const size_t MB = 1u << 20;
  unsigned short* xb   = (unsigned short*)(ws + 0 * MB);   // 8 MB
  unsigned short* Wcat = (unsigned short*)(ws + 8 * MB);   // 4 x 2 MB: Wq,Wk,Wv,Wo
  unsigned short* Qb   = (unsigned short*)(ws + 16 * MB);  // 8 MB
  unsigned short* Kb   = (unsigned short*)(ws + 24 * MB);  // 8 MB
  unsigned short* VTb  = (unsigned short*)(ws + 32 * MB);  // 8 MB
  unsigned short* Ob   = (unsigned short*)(ws + 40 * MB);  // 8 MB
  unsigned short* Wob  = Wcat + (size_t)3 * E_ * E_;

  cvt_all<<<dim3(1024, 8), 256, 0, stream>>>(x, Wq, Wk, Wv, Wo, xb, Wcat);

  gemm_qkv3<<<dim3(32, 24), 256, 0, stream>>>(xb, Wcat, bq, bk, bv, Qb, Kb, VTb);

  attn_kernel<<<dim3(S_ / 128, H_, B_), 512, 0, stream>>>(Qb, Kb, VTb, qw, qb, Ob);

  gemm_out64<<<dim3(64, 8), 256, 0, stream>>>(Ob, Wob, bo, out);
}